// Round 1
// baseline (335.645 us; speedup 1.0000x reference)
//
#include <hip/hip_runtime.h>

// LJ pair energy -> scatter onto first atom of each pair.
// en_atom[a] = 0.5 * sum_{p : ind2[p,0]==a} ( 4*eps*(c12 - c6) - e0 )
// with c6 = (sigma/dist)^6, c12 = c6^2, e0 = 4*eps*((sigma/rc)^12 - (sigma/rc)^6).
// sigma = eps = 1, rc = 3.
//
// Folded per-pair form (including the /2):
//   half_en = 2*(c6*c6 - c6) - 0.5*e0

// e0 = 4 * ((1/3)^12 - (1/3)^6); half = e0/2, computed in double then truncated.
#define HALF_E0f (-2.7397002f)  // 2*((1/3.)**12 - (1/3.)**6) = -2.7397002e-3... careful below

// Compute precisely: (1/3)^6 = 1.371742112482853e-3, (1/3)^12 = 1.8816764231589208e-6
// e0 = 4*(1.8816764231589208e-6 - 1.371742112482853e-3) = -5.479441744239576e-3
// e0/2 = -2.739720872119788e-3
static __device__ __forceinline__ float half_en(float d) {
    const float half_e0 = -2.739720872119788e-3f;
    float inv = 1.0f / d;
    float i2 = inv * inv;
    float i6 = i2 * i2 * i2;
    return 2.0f * (i6 * i6 - i6) - half_e0;
}

__global__ void lj_scatter_kernel(const float* __restrict__ dist,
                                  const int* __restrict__ ind2,
                                  float* __restrict__ out,
                                  int n_pairs) {
    int t = blockIdx.x * blockDim.x + threadIdx.x;
    int i = t * 4;
    if (i >= n_pairs) return;

    if (i + 4 <= n_pairs) {
        // 4 pairs: dist as float4, indices as two int4 (pairs interleaved [p][2])
        float4 d = *reinterpret_cast<const float4*>(dist + i);
        int4 ia = *reinterpret_cast<const int4*>(ind2 + 2 * i);      // pairs i, i+1
        int4 ib = *reinterpret_cast<const int4*>(ind2 + 2 * i + 4);  // pairs i+2, i+3

        float e0v = half_en(d.x);
        float e1v = half_en(d.y);
        float e2v = half_en(d.z);
        float e3v = half_en(d.w);

        atomicAdd(&out[ia.x], e0v);
        atomicAdd(&out[ia.z], e1v);
        atomicAdd(&out[ib.x], e2v);
        atomicAdd(&out[ib.z], e3v);
    } else {
        for (int p = i; p < n_pairs; ++p) {
            float d = dist[p];
            int a = ind2[2 * p];
            atomicAdd(&out[a], half_en(d));
        }
    }
}

extern "C" void kernel_launch(void* const* d_in, const int* in_sizes, int n_in,
                              void* d_out, int out_size, void* d_ws, size_t ws_size,
                              hipStream_t stream) {
    const float* dist = (const float*)d_in[0];
    // d_in[1] = ind_1 (only its shape/natom matters; natom == out_size)
    const int* ind2 = (const int*)d_in[2];
    float* out = (float*)d_out;

    int n_pairs = in_sizes[0];

    // Zero the output accumulator every call (harness poisons d_out once and
    // never re-poisons between graph replays).
    hipMemsetAsync(d_out, 0, (size_t)out_size * sizeof(float), stream);

    int n_threads = (n_pairs + 3) / 4;
    int block = 256;
    int grid = (n_threads + block - 1) / block;
    lj_scatter_kernel<<<grid, block, 0, stream>>>(dist, ind2, out, n_pairs);
}

// Round 2
// 331.050 us; speedup vs baseline: 1.0139x; 1.0139x over previous
//
#include <hip/hip_runtime.h>

// LJ pair energy -> scatter onto first atom of each pair (segment_sum).
// Per-pair folded energy (includes the /2 and the cutoff shift):
//   half_en(d) = 2*((1/d)^12 - (1/d)^6) - e0/2,  e0/2 = -2.739720872119788e-3
//
// Round-2 structure: privatized, padded atomic accumulation.
//   d_ws = K copies of [natom][PAD] floats (PAD=8 -> 32 B per atom slot).
//   Scatter kernel: block b atomically adds into copy (b & (K-1)).
//   Reduce kernel: out[a] = sum_k ws[k][a][0].
// Rationale: 6.4M device atomics onto a 400 KB array serialize at the
// memory-side per-line (~1000 RMW/line). K=8 copies x 8-float padding
// spreads the same atomics over 64x more lines.

#define PAD 8

static __device__ __forceinline__ float half_en(float d) {
    const float half_e0 = -2.739720872119788e-3f;
    float inv = 1.0f / d;
    float i2 = inv * inv;
    float i6 = i2 * i2 * i2;
    return 2.0f * (i6 * i6 - i6) - half_e0;
}

__global__ void lj_scatter_priv(const float* __restrict__ dist,
                                const int* __restrict__ ind2,
                                float* __restrict__ ws,
                                int n_pairs, int natom, int kmask) {
    int t = blockIdx.x * blockDim.x + threadIdx.x;
    int i = t * 4;
    if (i >= n_pairs) return;

    float* copy = ws + (size_t)(blockIdx.x & kmask) * (size_t)natom * PAD;

    if (i + 4 <= n_pairs) {
        float4 d = *reinterpret_cast<const float4*>(dist + i);
        int4 ia = *reinterpret_cast<const int4*>(ind2 + 2 * i);      // pairs i, i+1
        int4 ib = *reinterpret_cast<const int4*>(ind2 + 2 * i + 4);  // pairs i+2, i+3

        float e0v = half_en(d.x);
        float e1v = half_en(d.y);
        float e2v = half_en(d.z);
        float e3v = half_en(d.w);

        atomicAdd(&copy[(size_t)ia.x * PAD], e0v);
        atomicAdd(&copy[(size_t)ia.z * PAD], e1v);
        atomicAdd(&copy[(size_t)ib.x * PAD], e2v);
        atomicAdd(&copy[(size_t)ib.z * PAD], e3v);
    } else {
        for (int p = i; p < n_pairs; ++p) {
            atomicAdd(&copy[(size_t)ind2[2 * p] * PAD], half_en(dist[p]));
        }
    }
}

__global__ void lj_reduce(const float* __restrict__ ws, float* __restrict__ out,
                          int natom, int K) {
    int a = blockIdx.x * blockDim.x + threadIdx.x;
    if (a >= natom) return;
    float s = 0.0f;
    for (int k = 0; k < K; ++k) {
        s += ws[(size_t)k * (size_t)natom * PAD + (size_t)a * PAD];
    }
    out[a] = s;
}

// Fallback (tiny ws): direct atomics into out.
__global__ void lj_scatter_direct(const float* __restrict__ dist,
                                  const int* __restrict__ ind2,
                                  float* __restrict__ out,
                                  int n_pairs) {
    int t = blockIdx.x * blockDim.x + threadIdx.x;
    int i = t * 4;
    if (i >= n_pairs) return;
    if (i + 4 <= n_pairs) {
        float4 d = *reinterpret_cast<const float4*>(dist + i);
        int4 ia = *reinterpret_cast<const int4*>(ind2 + 2 * i);
        int4 ib = *reinterpret_cast<const int4*>(ind2 + 2 * i + 4);
        atomicAdd(&out[ia.x], half_en(d.x));
        atomicAdd(&out[ia.z], half_en(d.y));
        atomicAdd(&out[ib.x], half_en(d.z));
        atomicAdd(&out[ib.z], half_en(d.w));
    } else {
        for (int p = i; p < n_pairs; ++p)
            atomicAdd(&out[ind2[2 * p]], half_en(dist[p]));
    }
}

extern "C" void kernel_launch(void* const* d_in, const int* in_sizes, int n_in,
                              void* d_out, int out_size, void* d_ws, size_t ws_size,
                              hipStream_t stream) {
    const float* dist = (const float*)d_in[0];
    // d_in[1] = ind_1 (unused: only its shape defines natom == out_size)
    const int* ind2 = (const int*)d_in[2];
    float* out = (float*)d_out;

    int n_pairs = in_sizes[0];
    int natom = out_size;

    size_t copy_bytes = (size_t)natom * PAD * sizeof(float);

    // Pick K = largest power of two <= 8 that fits in ws.
    int K = 0;
    for (int k = 8; k >= 1; k >>= 1) {
        if ((size_t)k * copy_bytes <= ws_size) { K = k; break; }
    }

    int n_threads = (n_pairs + 3) / 4;
    int block = 256;
    int grid = (n_threads + block - 1) / block;

    if (K == 0) {
        // ws too small: direct-atomic fallback (round-1 behavior).
        hipMemsetAsync(d_out, 0, (size_t)out_size * sizeof(float), stream);
        lj_scatter_direct<<<grid, block, 0, stream>>>(dist, ind2, out, n_pairs);
        return;
    }

    float* ws = (float*)d_ws;
    hipMemsetAsync(d_ws, 0, (size_t)K * copy_bytes, stream);

    lj_scatter_priv<<<grid, block, 0, stream>>>(dist, ind2, ws, n_pairs, natom, K - 1);

    int rblock = 256;
    int rgrid = (natom + rblock - 1) / rblock;
    lj_reduce<<<rgrid, rblock, 0, stream>>>(ws, out, natom, K);
}

// Round 3
// 64.255 us; speedup vs baseline: 5.2236x; 5.1521x over previous
//
#include <hip/hip_runtime.h>

// LJ pair energy -> segment-sum onto first atom of each pair, WITHOUT any
// device-scope atomics (round-2 showed the memory-side atomic engine caps at
// ~20.6 G atomics/s = 660 GB/s of 32B write-through; privatization was
// useless because the cost is per-op, not per-line).
//
// Pipeline (all integer-exact after per-pair fp32 energy -> fixed-point):
//   K1 lj_bin:   per 4096-pair block: energy q = round_rn(half_en(d) * 2^17),
//                bucket = atom >> 9 (512 atoms/bucket). LDS histogram +
//                Hillis-Steele scan + LDS cursor scatter groups records
//                (q<<9 | local_id, 4B) into this block's contiguous region.
//                Writes region coalesced + offset rows goffs[b][c].
//   K2 lj_bucket_reduce: block (slice s, bucket b): gather runs
//                [goffs[b][c], goffs[b+1][c]) from each region c in slice,
//                LDS-int-atomicAdd into acc[512], write int partial[s].
//   K3 lj_final: out[a] = (sum_s partial[s][a]) * 2^-17.
// Integer accumulation => bit-deterministic across replays.
//
// half_en(d) = 2*((1/d)^12 - (1/d)^6) - e0/2, e0/2 = -2.739720872119788e-3.
// |half_en| <= ~21.5 for d>=0.8 -> q fits 23 bits signed (clamped anyway).

#define CHUNK 4096
#define T1 256
#define APB 512              // atoms per bucket (9-bit local id)
#define QSCALE 131072.0f     // 2^17
#define S_SLICES 8

static __device__ __forceinline__ float half_en(float d) {
    const float half_e0 = -2.739720872119788e-3f;
    float inv = 1.0f / d;
    float i2 = inv * inv;
    float i6 = i2 * i2 * i2;
    return 2.0f * (i6 * i6 - i6) - half_e0;
}

static __device__ __forceinline__ int quant(float e) {
    int q = __float2int_rn(e * QSCALE);
    q = max(-4194304, min(4194303, q));  // keep within 23 signed bits
    return q;
}

__global__ __launch_bounds__(T1) void lj_bin(const float* __restrict__ dist,
                                             const int* __restrict__ ind2,
                                             unsigned* __restrict__ grec,
                                             unsigned* __restrict__ goffs,
                                             int n_pairs, int nblk, int nb) {
    __shared__ unsigned cnt[256];
    __shared__ unsigned offs[256];
    __shared__ unsigned cur[256];
    __shared__ unsigned recs[CHUNK];

    const int t = threadIdx.x;
    const int c = blockIdx.x;
    const int base = c * CHUNK;

    cnt[t] = 0;
    __syncthreads();

    unsigned rec[16];
    int bkt[16];

    // 4 groups; each thread handles 4 consecutive pairs per group (float4/int4).
    #pragma unroll
    for (int g = 0; g < 4; ++g) {
        const int p0 = base + g * (T1 * 4) + t * 4;
        float d0 = 0.f, d1 = 0.f, d2 = 0.f, d3 = 0.f;
        int i0 = 0, i1 = 0, i2 = 0, i3 = 0;
        if (p0 + 4 <= n_pairs) {
            float4 d = *reinterpret_cast<const float4*>(dist + p0);
            int4 ia = *reinterpret_cast<const int4*>(ind2 + 2 * p0);
            int4 ib = *reinterpret_cast<const int4*>(ind2 + 2 * p0 + 4);
            d0 = d.x; d1 = d.y; d2 = d.z; d3 = d.w;
            i0 = ia.x; i1 = ia.z; i2 = ib.x; i3 = ib.z;
        } else {
            if (p0 + 0 < n_pairs) { d0 = dist[p0 + 0]; i0 = ind2[2 * (p0 + 0)]; }
            if (p0 + 1 < n_pairs) { d1 = dist[p0 + 1]; i1 = ind2[2 * (p0 + 1)]; }
            if (p0 + 2 < n_pairs) { d2 = dist[p0 + 2]; i2 = ind2[2 * (p0 + 2)]; }
            if (p0 + 3 < n_pairs) { d3 = dist[p0 + 3]; i3 = ind2[2 * (p0 + 3)]; }
        }
        float dd[4] = {d0, d1, d2, d3};
        int ii[4] = {i0, i1, i2, i3};
        #pragma unroll
        for (int k = 0; k < 4; ++k) {
            const int j = g * 4 + k;
            if (p0 + k < n_pairs) {
                const int id = ii[k];
                const int b = id >> 9;
                const int q = quant(half_en(dd[k]));
                bkt[j] = b;
                rec[j] = (((unsigned)q) << 9) | (unsigned)(id & (APB - 1));
                atomicAdd(&cnt[b], 1u);
            } else {
                bkt[j] = -1;
                rec[j] = 0;
            }
        }
    }
    __syncthreads();

    const unsigned mycnt = cnt[t];
    // In-place Hillis-Steele inclusive scan over cnt[0..255].
    #pragma unroll
    for (int dlt = 1; dlt < 256; dlt <<= 1) {
        const unsigned x = (t >= dlt) ? cnt[t - dlt] : 0u;
        __syncthreads();
        cnt[t] += x;
        __syncthreads();
    }
    offs[t] = cnt[t] - mycnt;  // exclusive
    cur[t] = offs[t];
    __syncthreads();

    // Scatter records into LDS staging, grouped by bucket.
    #pragma unroll
    for (int j = 0; j < 16; ++j) {
        if (bkt[j] >= 0) {
            const unsigned pos = atomicAdd(&cur[bkt[j]], 1u);
            recs[pos] = rec[j];
        }
    }
    __syncthreads();

    // Coalesced region write + offset rows (row nb is the end sentinel).
    const int nv = min(CHUNK, n_pairs - base);
    for (int i = t; i < nv; i += T1)
        grec[(size_t)base + i] = recs[i];
    if (t <= nb)
        goffs[(size_t)t * nblk + c] = offs[t];
}

__global__ __launch_bounds__(256) void lj_bucket_reduce(const unsigned* __restrict__ grec,
                                                        const unsigned* __restrict__ goffs,
                                                        int* __restrict__ partial,
                                                        int nblk, int nb, int natom_pad, int cps) {
    __shared__ int acc[APB];
    const int t = threadIdx.x;
    const int b = blockIdx.x % nb;
    const int s = blockIdx.x / nb;

    acc[t] = 0;
    acc[t + 256] = 0;
    __syncthreads();

    const unsigned* r0 = goffs + (size_t)b * nblk;
    const unsigned* r1 = goffs + (size_t)(b + 1) * nblk;
    const int c0 = s * cps;
    const int c1 = min(nblk, c0 + cps);
    const int wv = t >> 6;
    const int ln = t & 63;

    for (int c = c0 + wv; c < c1; c += 4) {
        const unsigned o0 = r0[c];
        const unsigned o1 = r1[c];
        const size_t rb = (size_t)c * CHUNK;
        for (unsigned i = o0 + ln; i < o1; i += 64) {
            const unsigned r = grec[rb + i];
            atomicAdd(&acc[r & (APB - 1)], ((int)r) >> 9);
        }
    }
    __syncthreads();

    partial[(size_t)s * natom_pad + (size_t)b * APB + t] = acc[t];
    partial[(size_t)s * natom_pad + (size_t)b * APB + t + 256] = acc[t + 256];
}

__global__ void lj_final(const int* __restrict__ partial, float* __restrict__ out,
                         int natom, int natom_pad) {
    const int a = blockIdx.x * blockDim.x + threadIdx.x;
    if (a >= natom) return;
    int ssum = 0;
    #pragma unroll
    for (int s = 0; s < S_SLICES; ++s)
        ssum += partial[(size_t)s * natom_pad + a];
    out[a] = (float)ssum * (1.0f / QSCALE);
}

// Fallback: direct device atomics (round-1 behavior) if ws is too small.
__global__ void lj_scatter_direct(const float* __restrict__ dist,
                                  const int* __restrict__ ind2,
                                  float* __restrict__ out,
                                  int n_pairs) {
    int t = blockIdx.x * blockDim.x + threadIdx.x;
    int i = t * 4;
    if (i >= n_pairs) return;
    if (i + 4 <= n_pairs) {
        float4 d = *reinterpret_cast<const float4*>(dist + i);
        int4 ia = *reinterpret_cast<const int4*>(ind2 + 2 * i);
        int4 ib = *reinterpret_cast<const int4*>(ind2 + 2 * i + 4);
        atomicAdd(&out[ia.x], half_en(d.x));
        atomicAdd(&out[ia.z], half_en(d.y));
        atomicAdd(&out[ib.x], half_en(d.z));
        atomicAdd(&out[ib.z], half_en(d.w));
    } else {
        for (int p = i; p < n_pairs; ++p)
            atomicAdd(&out[ind2[2 * p]], half_en(dist[p]));
    }
}

extern "C" void kernel_launch(void* const* d_in, const int* in_sizes, int n_in,
                              void* d_out, int out_size, void* d_ws, size_t ws_size,
                              hipStream_t stream) {
    const float* dist = (const float*)d_in[0];
    // d_in[1] = ind_1: only its shape (natom == out_size) matters.
    const int* ind2 = (const int*)d_in[2];
    float* out = (float*)d_out;

    const int n_pairs = in_sizes[0];
    const int natom = out_size;

    const int nblk = (n_pairs + CHUNK - 1) / CHUNK;
    const int nb = (natom + APB - 1) / APB;
    const int natom_pad = nb * APB;
    const int cps = (nblk + S_SLICES - 1) / S_SLICES;

    const size_t rec_bytes = (size_t)nblk * CHUNK * sizeof(unsigned);
    const size_t offs_bytes = (size_t)(nb + 1) * nblk * sizeof(unsigned);
    const size_t part_bytes = (size_t)S_SLICES * natom_pad * sizeof(int);
    const size_t need = rec_bytes + offs_bytes + part_bytes;

    if (nb + 1 > 256 || need > ws_size) {
        // Fallback: direct atomics.
        hipMemsetAsync(d_out, 0, (size_t)out_size * sizeof(float), stream);
        int n_threads = (n_pairs + 3) / 4;
        int grid = (n_threads + 255) / 256;
        lj_scatter_direct<<<grid, 256, 0, stream>>>(dist, ind2, out, n_pairs);
        return;
    }

    unsigned* grec = (unsigned*)d_ws;
    unsigned* goffs = (unsigned*)((char*)d_ws + rec_bytes);
    int* partial = (int*)((char*)d_ws + rec_bytes + offs_bytes);

    lj_bin<<<nblk, T1, 0, stream>>>(dist, ind2, grec, goffs, n_pairs, nblk, nb);
    lj_bucket_reduce<<<S_SLICES * nb, 256, 0, stream>>>(grec, goffs, partial,
                                                        nblk, nb, natom_pad, cps);
    int fgrid = (natom + 255) / 256;
    lj_final<<<fgrid, 256, 0, stream>>>(partial, out, natom, natom_pad);
}

// Round 4
// 43.350 us; speedup vs baseline: 7.7427x; 1.4822x over previous
//
#include <hip/hip_runtime.h>

// LJ pair energy -> segment-sum onto first atom of each pair, no device atomics.
// Round-4: leaner counting-sort pipeline.
//   K1 lj_bin (512 thr, CHUNK=8192): q = round(half_en(d)*2^15) (21-bit signed),
//      bucket = atom>>11 (2048 atoms/bucket, nb=49). Single LDS-atomic round:
//      rank = atomicAdd(&cnt[b],1); single-wave shfl scan -> offs; grouped
//      records (q<<11 | local) placed at recs[offs[b]+rank]; uint4 region write.
//   K2 lj_bucket_reduce (32 slices x nb blocks): walk per-chunk runs
//      [goffs[b][c], goffs[b+1][c]) (avg ~167 recs = 668 B, coalesced),
//      LDS-int accumulate acc[2048], write int partial[s].
//   K3 lj_final: out[a] = (sum_s partial[s][a]) * 2^-15.
// Integer accumulation => bit-deterministic across graph replays.
//
// half_en(d) = 2*((1/d)^12 - (1/d)^6) - e0/2, e0/2 = -2.739720872119788e-3.
// |half_en| <= 21.5 for d >= 0.8 -> |q| <= ~704k < 2^20 (21-bit signed field).

#define CHUNK 8192
#define T1 512
#define ABITS 11
#define APB 2048            // atoms per bucket
#define NBMAX 63
#define QSCALE 32768.0f     // 2^15
#define QINV (1.0f / 32768.0f)
#define S_SLICES 32

static __device__ __forceinline__ float half_en(float d) {
    const float half_e0 = -2.739720872119788e-3f;
    float inv = 1.0f / d;
    float i2 = inv * inv;
    float i6 = i2 * i2 * i2;
    return 2.0f * (i6 * i6 - i6) - half_e0;
}

static __device__ __forceinline__ int quant(float e) {
    int q = __float2int_rn(e * QSCALE);
    return max(-1048576, min(1048575, q));  // 21-bit signed
}

__global__ __launch_bounds__(T1) void lj_bin(const float* __restrict__ dist,
                                             const int* __restrict__ ind2,
                                             unsigned* __restrict__ grec,
                                             unsigned* __restrict__ goffs,
                                             int n_pairs, int nblk, int nb) {
    __shared__ unsigned cnt[NBMAX + 1];
    __shared__ unsigned offs[NBMAX + 1];
    __shared__ unsigned recs[CHUNK];

    const int t = threadIdx.x;
    const int c = blockIdx.x;
    const int base = c * CHUNK;

    if (t <= NBMAX) cnt[t] = 0;
    __syncthreads();

    unsigned rec[16];
    unsigned br[16];  // (bucket<<16) | rank ; 0xFFFFFFFF = invalid

    #pragma unroll
    for (int g = 0; g < 4; ++g) {
        const int p0 = base + g * (T1 * 4) + t * 4;
        float dd[4] = {0.f, 0.f, 0.f, 0.f};
        int ii[4] = {0, 0, 0, 0};
        if (p0 + 4 <= n_pairs) {
            float4 d = *reinterpret_cast<const float4*>(dist + p0);
            int4 ia = *reinterpret_cast<const int4*>(ind2 + 2 * p0);
            int4 ib = *reinterpret_cast<const int4*>(ind2 + 2 * p0 + 4);
            dd[0] = d.x; dd[1] = d.y; dd[2] = d.z; dd[3] = d.w;
            ii[0] = ia.x; ii[1] = ia.z; ii[2] = ib.x; ii[3] = ib.z;
        } else {
            #pragma unroll
            for (int k = 0; k < 4; ++k)
                if (p0 + k < n_pairs) { dd[k] = dist[p0 + k]; ii[k] = ind2[2 * (p0 + k)]; }
        }
        #pragma unroll
        for (int k = 0; k < 4; ++k) {
            const int j = g * 4 + k;
            if (p0 + k < n_pairs) {
                const int id = ii[k];
                const int b = id >> ABITS;
                const int q = quant(half_en(dd[k]));
                rec[j] = (((unsigned)q) << ABITS) | (unsigned)(id & (APB - 1));
                const unsigned rank = atomicAdd(&cnt[b], 1u);  // rank within bucket
                br[j] = ((unsigned)b << 16) | rank;            // rank < 8192 fits
            } else {
                br[j] = 0xFFFFFFFFu;
                rec[j] = 0;
            }
        }
    }
    __syncthreads();

    // Exclusive scan of cnt[0..63] by wave 0 (shfl, no barriers inside).
    if (t < 64) {
        const unsigned v = cnt[t];
        unsigned inc = v;
        #pragma unroll
        for (int d = 1; d < 64; d <<= 1) {
            const unsigned x = __shfl_up(inc, d, 64);
            if (t >= d) inc += x;
        }
        offs[t] = inc - v;
    }
    __syncthreads();

    // Place records grouped by bucket (no second atomic round).
    #pragma unroll
    for (int j = 0; j < 16; ++j) {
        if (br[j] != 0xFFFFFFFFu) {
            const unsigned pos = offs[br[j] >> 16] + (br[j] & 0xFFFFu);
            recs[pos] = rec[j];
        }
    }
    __syncthreads();

    const int nv = min(CHUNK, n_pairs - base);
    // Vectorized coalesced region write.
    for (int i4 = t * 4; i4 + 4 <= nv; i4 += T1 * 4) {
        uint4 v = *reinterpret_cast<const uint4*>(&recs[i4]);
        *reinterpret_cast<uint4*>(&grec[(size_t)base + i4]) = v;
    }
    for (int i = (nv & ~3) + t; i < nv; i += T1)
        grec[(size_t)base + i] = recs[i];
    if (t <= nb)
        goffs[(size_t)t * nblk + c] = offs[t];  // row nb = end sentinel (=nv)
}

__global__ __launch_bounds__(256) void lj_bucket_reduce(const unsigned* __restrict__ grec,
                                                        const unsigned* __restrict__ goffs,
                                                        int* __restrict__ partial,
                                                        int nblk, int nb, int natom_pad,
                                                        int cps) {
    __shared__ int acc[APB];
    const int t = threadIdx.x;
    const int b = blockIdx.x % nb;
    const int s = blockIdx.x / nb;

    #pragma unroll
    for (int k = 0; k < APB / 256; ++k) acc[t + k * 256] = 0;
    __syncthreads();

    const unsigned* r0 = goffs + (size_t)b * nblk;
    const unsigned* r1 = goffs + (size_t)(b + 1) * nblk;
    const int c0 = s * cps;
    const int c1 = min(nblk, c0 + cps);
    const int wv = t >> 6;
    const int ln = t & 63;

    for (int c = c0 + wv; c < c1; c += 4) {
        const unsigned o0 = r0[c];
        const unsigned o1 = r1[c];
        const size_t rb = (size_t)c * CHUNK;
        for (unsigned i = o0 + ln; i < o1; i += 64) {
            const unsigned r = grec[rb + i];
            atomicAdd(&acc[r & (APB - 1)], ((int)r) >> ABITS);
        }
    }
    __syncthreads();

    int* dst = partial + (size_t)s * natom_pad + (size_t)b * APB;
    #pragma unroll
    for (int k = 0; k < APB / 256; ++k) dst[t + k * 256] = acc[t + k * 256];
}

__global__ void lj_final(const int* __restrict__ partial, float* __restrict__ out,
                         int natom, int natom_pad) {
    const int a = blockIdx.x * blockDim.x + threadIdx.x;
    if (a >= natom) return;
    int ssum = 0;
    #pragma unroll
    for (int s = 0; s < S_SLICES; ++s)
        ssum += partial[(size_t)s * natom_pad + a];
    out[a] = (float)ssum * QINV;
}

// Fallback: direct device atomics if ws too small / shape unexpected.
__global__ void lj_scatter_direct(const float* __restrict__ dist,
                                  const int* __restrict__ ind2,
                                  float* __restrict__ out,
                                  int n_pairs) {
    int t = blockIdx.x * blockDim.x + threadIdx.x;
    int i = t * 4;
    if (i >= n_pairs) return;
    if (i + 4 <= n_pairs) {
        float4 d = *reinterpret_cast<const float4*>(dist + i);
        int4 ia = *reinterpret_cast<const int4*>(ind2 + 2 * i);
        int4 ib = *reinterpret_cast<const int4*>(ind2 + 2 * i + 4);
        atomicAdd(&out[ia.x], half_en(d.x));
        atomicAdd(&out[ia.z], half_en(d.y));
        atomicAdd(&out[ib.x], half_en(d.z));
        atomicAdd(&out[ib.z], half_en(d.w));
    } else {
        for (int p = i; p < n_pairs; ++p)
            atomicAdd(&out[ind2[2 * p]], half_en(dist[p]));
    }
}

extern "C" void kernel_launch(void* const* d_in, const int* in_sizes, int n_in,
                              void* d_out, int out_size, void* d_ws, size_t ws_size,
                              hipStream_t stream) {
    const float* dist = (const float*)d_in[0];
    // d_in[1] = ind_1: only its shape (natom == out_size) matters.
    const int* ind2 = (const int*)d_in[2];
    float* out = (float*)d_out;

    const int n_pairs = in_sizes[0];
    const int natom = out_size;

    const int nblk = (n_pairs + CHUNK - 1) / CHUNK;
    const int nb = (natom + APB - 1) / APB;
    const int natom_pad = nb * APB;
    const int cps = (nblk + S_SLICES - 1) / S_SLICES;

    const size_t rec_bytes = (size_t)nblk * CHUNK * sizeof(unsigned);
    const size_t offs_bytes = (size_t)(nb + 1) * nblk * sizeof(unsigned);
    const size_t part_bytes = (size_t)S_SLICES * natom_pad * sizeof(int);
    const size_t need = rec_bytes + offs_bytes + part_bytes;

    if (nb > NBMAX || need > ws_size) {
        hipMemsetAsync(d_out, 0, (size_t)out_size * sizeof(float), stream);
        int n_threads = (n_pairs + 3) / 4;
        int grid = (n_threads + 255) / 256;
        lj_scatter_direct<<<grid, 256, 0, stream>>>(dist, ind2, out, n_pairs);
        return;
    }

    unsigned* grec = (unsigned*)d_ws;
    unsigned* goffs = (unsigned*)((char*)d_ws + rec_bytes);
    int* partial = (int*)((char*)d_ws + rec_bytes + offs_bytes);

    lj_bin<<<nblk, T1, 0, stream>>>(dist, ind2, grec, goffs, n_pairs, nblk, nb);
    lj_bucket_reduce<<<S_SLICES * nb, 256, 0, stream>>>(grec, goffs, partial,
                                                        nblk, nb, natom_pad, cps);
    int fgrid = (natom + 255) / 256;
    lj_final<<<fgrid, 256, 0, stream>>>(partial, out, natom, natom_pad);
}

// Round 5
// 43.214 us; speedup vs baseline: 7.7670x; 1.0031x over previous
//
#include <hip/hip_runtime.h>

// LJ pair energy -> segment-sum onto first atom of each pair, no device atomics.
// Round-5: smaller buckets, leaner partials, LDS-cached offset rows.
//   K1 lj_bin (512 thr, CHUNK=8192): q = round(half_en(d)*2^15) (23-bit clamp),
//      bucket = atom>>9 (512 atoms/bucket, nb=196). rank = atomicAdd(&cnt[b],1);
//      multi-wave shfl scan over 256 counters -> offs; records (q<<9 | local)
//      grouped in LDS at offs[b]+rank; uint4 coalesced region write + offset row.
//   K2 lj_bucket_reduce (8 slices x 196 buckets, 256 thr): preload the two
//      offset rows for this bucket into LDS, walk runs [lo[c], hi[c]) of the
//      slice's chunks (contiguous ~170B reads), LDS-int accumulate acc[512],
//      write int partial[s].
//   K3 lj_final: out[a] = (sum_{s<8} partial[s][a]) * 2^-15.
// Integer accumulation => bit-deterministic across graph replays.
//
// half_en(d) = 2*((1/d)^12 - (1/d)^6) - e0/2, e0/2 = -2.739720872119788e-3.
// |half_en| <= 21.5 for d >= 0.8 -> |q| <= ~705k < 2^22 (23-bit signed field).

#define CHUNK 8192
#define T1 512
#define ABITS 9
#define APB 512             // atoms per bucket
#define NBMAX 255           // nb+1 <= 256
#define QSCALE 32768.0f     // 2^15
#define QINV (1.0f / 32768.0f)
#define S_SLICES 8

static __device__ __forceinline__ float half_en(float d) {
    const float half_e0 = -2.739720872119788e-3f;
    float inv = 1.0f / d;
    float i2 = inv * inv;
    float i6 = i2 * i2 * i2;
    return 2.0f * (i6 * i6 - i6) - half_e0;
}

static __device__ __forceinline__ int quant(float e) {
    int q = __float2int_rn(e * QSCALE);
    return max(-4194304, min(4194303, q));  // 23-bit signed
}

__global__ __launch_bounds__(T1) void lj_bin(const float* __restrict__ dist,
                                             const int* __restrict__ ind2,
                                             unsigned* __restrict__ grec,
                                             unsigned* __restrict__ goffs,
                                             int n_pairs, int nblk, int nb) {
    __shared__ unsigned cnt[256];
    __shared__ unsigned offs[256];
    __shared__ unsigned wsum[4];
    __shared__ unsigned recs[CHUNK];

    const int t = threadIdx.x;
    const int c = blockIdx.x;
    const int base = c * CHUNK;

    if (t < 256) cnt[t] = 0;
    __syncthreads();

    unsigned rec[16];
    unsigned br[16];  // (bucket<<16) | rank ; 0xFFFFFFFF = invalid

    #pragma unroll
    for (int g = 0; g < 4; ++g) {
        const int p0 = base + g * (T1 * 4) + t * 4;
        float dd[4] = {0.f, 0.f, 0.f, 0.f};
        int ii[4] = {0, 0, 0, 0};
        if (p0 + 4 <= n_pairs) {
            float4 d = *reinterpret_cast<const float4*>(dist + p0);
            int4 ia = *reinterpret_cast<const int4*>(ind2 + 2 * p0);
            int4 ib = *reinterpret_cast<const int4*>(ind2 + 2 * p0 + 4);
            dd[0] = d.x; dd[1] = d.y; dd[2] = d.z; dd[3] = d.w;
            ii[0] = ia.x; ii[1] = ia.z; ii[2] = ib.x; ii[3] = ib.z;
        } else {
            #pragma unroll
            for (int k = 0; k < 4; ++k)
                if (p0 + k < n_pairs) { dd[k] = dist[p0 + k]; ii[k] = ind2[2 * (p0 + k)]; }
        }
        #pragma unroll
        for (int k = 0; k < 4; ++k) {
            const int j = g * 4 + k;
            if (p0 + k < n_pairs) {
                const int id = ii[k];
                const int b = id >> ABITS;
                const int q = quant(half_en(dd[k]));
                rec[j] = (((unsigned)q) << ABITS) | (unsigned)(id & (APB - 1));
                const unsigned rank = atomicAdd(&cnt[b], 1u);  // rank within bucket
                br[j] = ((unsigned)b << 16) | rank;            // rank < 8192 fits
            } else {
                br[j] = 0xFFFFFFFFu;
                rec[j] = 0;
            }
        }
    }
    __syncthreads();

    // Exclusive scan of cnt[0..255]: per-wave shfl scan + wave-total fixup.
    {
        const unsigned v = (t < 256) ? cnt[t] : 0u;
        unsigned inc = v;
        #pragma unroll
        for (int d = 1; d < 64; d <<= 1) {
            const unsigned x = __shfl_up(inc, d, 64);
            if ((t & 63) >= d) inc += x;
        }
        if (t < 256 && (t & 63) == 63) wsum[t >> 6] = inc;
        __syncthreads();
        if (t < 256) {
            unsigned add = 0;
            #pragma unroll
            for (int j = 0; j < 4; ++j)
                if (j < (t >> 6)) add += wsum[j];
            offs[t] = add + inc - v;  // exclusive
        }
    }
    __syncthreads();

    // Place records grouped by bucket (single atomic round; rank trick).
    #pragma unroll
    for (int j = 0; j < 16; ++j) {
        if (br[j] != 0xFFFFFFFFu) {
            const unsigned pos = offs[br[j] >> 16] + (br[j] & 0xFFFFu);
            recs[pos] = rec[j];
        }
    }
    __syncthreads();

    const int nv = min(CHUNK, n_pairs - base);
    for (int i4 = t * 4; i4 + 4 <= nv; i4 += T1 * 4) {
        uint4 v = *reinterpret_cast<const uint4*>(&recs[i4]);
        *reinterpret_cast<uint4*>(&grec[(size_t)base + i4]) = v;
    }
    for (int i = (nv & ~3) + t; i < nv; i += T1)
        grec[(size_t)base + i] = recs[i];
    if (t <= nb)
        goffs[(size_t)t * nblk + c] = offs[t];  // row nb = end sentinel (=nv)
}

#define T2 256

__global__ __launch_bounds__(T2) void lj_bucket_reduce(const unsigned* __restrict__ grec,
                                                       const unsigned* __restrict__ goffs,
                                                       int* __restrict__ partial,
                                                       int nblk, int nb, int natom_pad,
                                                       int cps) {
    __shared__ int acc[APB];
    extern __shared__ unsigned dynoffs[];  // lo[cps] ++ hi[cps]

    const int t = threadIdx.x;
    const int b = blockIdx.x % nb;
    const int s = blockIdx.x / nb;

    #pragma unroll
    for (int k = 0; k < APB / T2; ++k) acc[t + k * T2] = 0;

    const int c0 = s * cps;
    const int cn = min(nblk - c0, cps);
    if (cn <= 0) {  // still must write zeros
        __syncthreads();
        int* dst = partial + (size_t)s * natom_pad + (size_t)b * APB;
        #pragma unroll
        for (int k = 0; k < APB / T2; ++k) dst[t + k * T2] = acc[t + k * T2];
        return;
    }

    unsigned* lo = dynoffs;
    unsigned* hi = dynoffs + cps;
    const unsigned* r0 = goffs + (size_t)b * nblk + c0;
    const unsigned* r1 = goffs + (size_t)(b + 1) * nblk + c0;
    for (int i = t; i < cn; i += T2) {
        lo[i] = r0[i];
        hi[i] = r1[i];
    }
    __syncthreads();

    const int wv = t >> 6;
    const int ln = t & 63;

    for (int c = wv; c < cn; c += T2 / 64) {
        const unsigned o0 = lo[c];
        const unsigned o1 = hi[c];
        const size_t rb = (size_t)(c0 + c) * CHUNK;
        for (unsigned i = o0 + ln; i < o1; i += 64) {
            const unsigned r = grec[rb + i];
            atomicAdd(&acc[r & (APB - 1)], ((int)r) >> ABITS);
        }
    }
    __syncthreads();

    int* dst = partial + (size_t)s * natom_pad + (size_t)b * APB;
    #pragma unroll
    for (int k = 0; k < APB / T2; ++k) dst[t + k * T2] = acc[t + k * T2];
}

__global__ void lj_final(const int* __restrict__ partial, float* __restrict__ out,
                         int natom, int natom_pad) {
    const int a = blockIdx.x * blockDim.x + threadIdx.x;
    if (a >= natom) return;
    int ssum = 0;
    #pragma unroll
    for (int s = 0; s < S_SLICES; ++s)
        ssum += partial[(size_t)s * natom_pad + a];
    out[a] = (float)ssum * QINV;
}

// Fallback: direct device atomics if ws too small / shape unexpected.
__global__ void lj_scatter_direct(const float* __restrict__ dist,
                                  const int* __restrict__ ind2,
                                  float* __restrict__ out,
                                  int n_pairs) {
    int t = blockIdx.x * blockDim.x + threadIdx.x;
    int i = t * 4;
    if (i >= n_pairs) return;
    if (i + 4 <= n_pairs) {
        float4 d = *reinterpret_cast<const float4*>(dist + i);
        int4 ia = *reinterpret_cast<const int4*>(ind2 + 2 * i);
        int4 ib = *reinterpret_cast<const int4*>(ind2 + 2 * i + 4);
        atomicAdd(&out[ia.x], half_en(d.x));
        atomicAdd(&out[ia.z], half_en(d.y));
        atomicAdd(&out[ib.x], half_en(d.z));
        atomicAdd(&out[ib.z], half_en(d.w));
    } else {
        for (int p = i; p < n_pairs; ++p)
            atomicAdd(&out[ind2[2 * p]], half_en(dist[p]));
    }
}

extern "C" void kernel_launch(void* const* d_in, const int* in_sizes, int n_in,
                              void* d_out, int out_size, void* d_ws, size_t ws_size,
                              hipStream_t stream) {
    const float* dist = (const float*)d_in[0];
    // d_in[1] = ind_1: only its shape (natom == out_size) matters.
    const int* ind2 = (const int*)d_in[2];
    float* out = (float*)d_out;

    const int n_pairs = in_sizes[0];
    const int natom = out_size;

    const int nblk = (n_pairs + CHUNK - 1) / CHUNK;
    const int nb = (natom + APB - 1) / APB;
    const int natom_pad = nb * APB;
    const int cps = (nblk + S_SLICES - 1) / S_SLICES;

    const size_t rec_bytes = (size_t)nblk * CHUNK * sizeof(unsigned);
    const size_t offs_bytes = (size_t)(nb + 1) * nblk * sizeof(unsigned);
    const size_t part_bytes = (size_t)S_SLICES * natom_pad * sizeof(int);
    const size_t need = rec_bytes + offs_bytes + part_bytes;
    const size_t dyn_lds = 2u * (size_t)cps * sizeof(unsigned);

    if (nb + 1 > 256 || need > ws_size || dyn_lds > 64 * 1024) {
        hipMemsetAsync(d_out, 0, (size_t)out_size * sizeof(float), stream);
        int n_threads = (n_pairs + 3) / 4;
        int grid = (n_threads + 255) / 256;
        lj_scatter_direct<<<grid, 256, 0, stream>>>(dist, ind2, out, n_pairs);
        return;
    }

    unsigned* grec = (unsigned*)d_ws;
    unsigned* goffs = (unsigned*)((char*)d_ws + rec_bytes);
    int* partial = (int*)((char*)d_ws + rec_bytes + offs_bytes);

    lj_bin<<<nblk, T1, 0, stream>>>(dist, ind2, grec, goffs, n_pairs, nblk, nb);
    lj_bucket_reduce<<<S_SLICES * nb, T2, dyn_lds, stream>>>(grec, goffs, partial,
                                                             nblk, nb, natom_pad, cps);
    int fgrid = (natom + 255) / 256;
    lj_final<<<fgrid, 256, 0, stream>>>(partial, out, natom, natom_pad);
}